// Round 25
// baseline (25.480 us; speedup 1.0000x reference)
//
#include <hip/hip_runtime.h>
#include <math.h>

#define NC 2048            // 2H + 2W (H = W = 512)
#define NB 4
#define NS 4096
#define INV_TEMP (1.0f / 256.0f)
#define LOG2E 1.44269504088896340736f
#define CL 16              // chunk length (rows per loss block)
#define NCH (NS / CL)      // 256 chunks per batch
#define LOSS_NBLK (NB * NCH)   // 1024 loss blocks

typedef float f32x4 __attribute__((ext_vector_type(4)));

// 64-lane wave sum on the VALU pipe (DPP), no DS-pipe traffic. (R16.)
#define WAVE_SUM_DPP(x)                                                       \
    asm volatile("s_nop 1\n\t"                                                \
                 "v_add_f32 %0, %0, %0 row_shr:1 bound_ctrl:0" : "+v"(x));    \
    asm volatile("s_nop 1\n\t"                                                \
                 "v_add_f32 %0, %0, %0 row_shr:2 bound_ctrl:0" : "+v"(x));    \
    asm volatile("s_nop 1\n\t"                                                \
                 "v_add_f32 %0, %0, %0 row_shr:4 bound_ctrl:0" : "+v"(x));    \
    asm volatile("s_nop 1\n\t"                                                \
                 "v_add_f32 %0, %0, %0 row_shr:8 bound_ctrl:0" : "+v"(x));    \
    asm volatile("s_nop 1\n\t"                                                \
                 "v_add_f32 %0, %0, %0 row_bcast:15 row_mask:0xa" : "+v"(x)); \
    asm volatile("s_nop 1\n\t"                                                \
                 "v_add_f32 %0, %0, %0 row_bcast:31 row_mask:0xc" : "+v"(x));

__device__ __forceinline__ float wave_total(float x)
{
    return __uint_as_float(__builtin_amdgcn_readlane(__float_as_uint(x), 63));
}

// ---------------------------------------------------------------------------
// Single fused kernel (R24 structure). Final head fix: VECTORIZED ev staging
// — 17 threads load one f32x4 row each (1 coalesced instr) instead of 16
// threads x 5 dependent scalar loads; dec computation (tid<16) overlaps the
// scatter-atomic phase (ev is only consumed after the second barrier).
// ---------------------------------------------------------------------------
__global__ __launch_bounds__(256) void tdl_loss_kernel(
    const float* __restrict__ pred, const float* __restrict__ target,
    float* __restrict__ partials)
{
    const int blk = blockIdx.x;
    const int b = blk >> 8;              // / NCH
    const int k = blk & (NCH - 1);
    const int s0 = k * CL;
    const int tid = threadIdx.x;
    const int wv  = (tid >> 6) & 1;      // 0: H-pair, 1: W-pair
    const int rh  = tid >> 7;            // 0: rows 15..8, 1: rows 7..0
    const int ln  = tid & 63;

    __shared__ float accs[NC];           // 8 KiB sparse-carry accumulator
    __shared__ f32x4 evraw[CL + 1];      // staged {t,h,w,p}
    __shared__ f32x4 ev[CL];             // {dec, p, h, w}
    __shared__ float sh4[4];

    const int lc   = ln * 4;             // lane offset within a 256-ch quarter
    const int segA = wv * 2;             // even segment of my pair
    const size_t pbase = (size_t)b * NS * NC;
    const int itop = rh ? (CL / 2 - 1) : (CL - 1);  // 7 or 15

    // ---- ISSUE FIRST: scatter loads (zero deps; latency hides under head)
    const int sc = s0 + CL + tid;
    f32x4 evt = {0.0f, 0.0f, 0.0f, 0.0f};
    float tb0 = 0.0f;
    const bool sc_ok = (sc < NS);
    if (sc_ok) {
        evt = *((const f32x4*)target + (size_t)b * NS + sc);
        tb0 = target[((size_t)b * NS + s0 + CL) * 4];
    }

    // ---- EARLY global p for my first two rows -> pred prefetch issues
    //      before the staging barrier.
    const float pt0 = target[((size_t)b * NS + s0 + itop) * 4 + 3];
    const float pt1 = target[((size_t)b * NS + s0 + itop - 1) * 4 + 3];
    f32x4 pf0[2], pf1[2];
    {
        const float* pr = pred + pbase + (size_t)(s0 + itop) * NC
                          + (segA + (int)pt0) * 512 + lc;
        pf0[0] = *(const f32x4*)pr; pf0[1] = *(const f32x4*)(pr + 256);
        const float* pr2 = pred + pbase + (size_t)(s0 + itop - 1) * NC
                           + (segA + (int)pt1) * 512 + lc;
        pf1[0] = *(const f32x4*)pr2; pf1[1] = *(const f32x4*)(pr2 + 256);
    }

    // ---- head: zero acc + vectorized evraw staging (1 f32x4/thread)
    {
        f32x4 z = {0.0f, 0.0f, 0.0f, 0.0f};
        ((f32x4*)accs)[tid] = z;
        ((f32x4*)accs)[256 + tid] = z;
    }
    if (tid <= CL) {
        int s = s0 + tid;
        if (s < NS) evraw[tid] = *((const f32x4*)target + (size_t)b * NS + s);
        else        { f32x4 z = {0.0f, 0.0f, 0.0f, 0.0f}; evraw[tid] = z; }
    }
    __syncthreads();

    // ---- ev derivation (tid<16) overlaps the scatter atomics below
    if (tid < CL) {
        f32x4 r = evraw[tid];
        int s = s0 + tid;
        float dec = (s == NS - 1 || s == 0) ? 0.0f
                   : __expf(-(evraw[tid + 1].x - r.x) * INV_TEMP);
        f32x4 e; e.x = dec; e.y = r.w; e.z = r.y; e.w = r.z;  // {dec,p,h,w}
        ev[tid] = e;
    }

    // ---- sparse carry scatter (evt already in registers)
    if (sc_ok) {
        const float w = __expf(-(evt.x - tb0) * INV_TEMP);
        const int hh = (int)evt.y;
        const int ww = (int)evt.z;
        if (evt.w != 0.0f) {             // p==1 -> segments H1, W1
            atomicAdd(&accs[512 + hh], w);
            atomicAdd(&accs[1536 + ww], w);
        } else {                         // p==0 -> segments H0, W0
            atomicAdd(&accs[hh], w);
            atomicAdd(&accs[1024 + ww], w);
        }
    }
    __syncthreads();

    // ---- carry read: vA/vB from acc (exp2 domain)
    float vA[8], vB[8];
#pragma unroll
    for (int q = 0; q < 2; ++q) {
        f32x4 ra = *(const f32x4*)&accs[segA * 512 + q * 256 + lc];
        f32x4 rb = *(const f32x4*)&accs[(segA + 1) * 512 + q * 256 + lc];
#pragma unroll
        for (int j = 0; j < 4; ++j) {
            vA[q*4+j] = ra[j] * LOG2E;
            vB[q*4+j] = rb[j] * LOG2E;
        }
    }

    // rh=1 waves: replay rows 15..8 scan-only to derive carry at row 7
    if (rh) {
#pragma unroll
        for (int i = CL - 1; i >= CL / 2; --i) {
            f32x4 e = ev[i];
            const float d    = e.x;
            const float pv   = e.y;
            const float idxf = wv ? e.w : e.z;
            const float aA = (1.0f - pv) * LOG2E;
            const float aB = pv * LOG2E;
#pragma unroll
            for (int q = 0; q < 2; ++q) {
#pragma unroll
                for (int j = 0; j < 4; ++j) {
                    const int id = q * 4 + j;
                    const float myc = (float)(q * 256 + lc + j);
                    const bool m = (idxf == myc);
                    vA[id] = fmaf(vA[id], d, m ? aA : 0.0f);
                    vB[id] = fmaf(vB[id], d, m ? aB : 0.0f);
                }
            }
        }
    }

    float acc = 0.0f;
#pragma unroll
    for (int r = 0; r < 8; ++r) {
        const int i = itop - r;
        f32x4 cur0 = pf0[0], cur1 = pf0[1];
        pf0[0] = pf1[0]; pf0[1] = pf1[1];
        if (r < 6) {                     // row i-2 still in my range
            const int pa = (int)ev[i - 2].y;
            const float* pr = pred + pbase + (size_t)(s0 + i - 2) * NC
                              + (segA + pa) * 512 + lc;
            pf1[0] = *(const f32x4*)pr; pf1[1] = *(const f32x4*)(pr + 256);
        }

        f32x4 e = ev[i];
        const float d    = e.x;
        const float pv   = e.y;                    // 0.0 or 1.0 exactly
        const float idxf = wv ? e.w : e.z;         // w for W-pair, h for H-pair
        const float aA = (1.0f - pv) * LOG2E;
        const float aB = pv * LOG2E;

        float ser = 0.0f, dot = 0.0f, sep = 0.0f;
#pragma unroll
        for (int q = 0; q < 2; ++q) {
            const f32x4 cq = q ? cur1 : cur0;
#pragma unroll
            for (int j = 0; j < 4; ++j) {
                const int id = q * 4 + j;
                const float myc = (float)(q * 256 + lc + j);
                const bool m = (idxf == myc);
                vA[id] = fmaf(vA[id], d, m ? aA : 0.0f);  // scan both segs
                vB[id] = fmaf(vB[id], d, m ? aB : 0.0f);
                const float vs = (pv != 0.0f) ? vB[id] : vA[id];  // active
                const float ex = exp2f(vs);
                const float pj = cq[j];
                ser += ex;
                dot = fmaf(ex, pj, dot);
                sep += __expf(pj);
            }
        }

        // 64-lane reductions on the VALU pipe (DPP), no DS traffic
        WAVE_SUM_DPP(ser)
        WAVE_SUM_DPP(dot)
        WAVE_SUM_DPP(sep)
        const float serT = wave_total(ser);
        const float dotT = wave_total(dot);
        const float sepT = wave_total(sep);
        acc += __logf(sepT) - dotT * __builtin_amdgcn_rcpf(serT);
    }

    if (ln == 0) sh4[tid >> 6] = acc;    // one writer per wave
    __syncthreads();
    if (tid == 0) partials[blk] = sh4[0] + sh4[1] + sh4[2] + sh4[3];
}

// ---------------------------------------------------------------------------
// Tiny reduce — 1 block, 256 threads, 4 KB of partials -> out[0].
// ---------------------------------------------------------------------------
__global__ __launch_bounds__(256) void tdl_reduce_kernel(
    const float* __restrict__ partials, float* __restrict__ out)
{
    const int tid = threadIdx.x;
    __shared__ float sh4[4];

    float s = 0.0f;
#pragma unroll
    for (int i = 0; i < LOSS_NBLK / 256; ++i)
        s += partials[i * 256 + tid];
#pragma unroll
    for (int off = 32; off > 0; off >>= 1)
        s += __shfl_xor(s, off, 64);
    if ((tid & 63) == 0) sh4[tid >> 6] = s;
    __syncthreads();
    if (tid == 0)
        out[0] = (sh4[0] + sh4[1] + sh4[2] + sh4[3])
                 * (1.0f / ((float)NB * (float)NS));
}

// ---------------------------------------------------------------------------
extern "C" void kernel_launch(void* const* d_in, const int* in_sizes, int n_in,
                              void* d_out, int out_size, void* d_ws, size_t ws_size,
                              hipStream_t stream)
{
    const float* pred   = (const float*)d_in[0];
    const float* target = (const float*)d_in[1];
    float* out      = (float*)d_out;
    float* partials = (float*)d_ws;      // 4 KiB

    tdl_loss_kernel<<<NB * NCH, 256, 0, stream>>>(pred, target, partials);
    tdl_reduce_kernel<<<1, 256, 0, stream>>>(partials, out);
}

// Round 26
// 24.781 us; speedup vs baseline: 1.0282x; 1.0282x over previous
//
#include <hip/hip_runtime.h>
#include <math.h>

#define NC 2048            // 2H + 2W (H = W = 512)
#define NB 4
#define NS 4096
#define INV_TEMP (1.0f / 256.0f)
#define LOG2E 1.44269504088896340736f
#define CL 16              // chunk length (rows per loss block)
#define NCH (NS / CL)      // 256 chunks per batch
#define LOSS_NBLK (NB * NCH)   // 1024 loss blocks

typedef float f32x4 __attribute__((ext_vector_type(4)));

// 64-lane wave sum on the VALU pipe (DPP), no DS-pipe traffic. (R16.)
#define WAVE_SUM_DPP(x)                                                       \
    asm volatile("s_nop 1\n\t"                                                \
                 "v_add_f32 %0, %0, %0 row_shr:1 bound_ctrl:0" : "+v"(x));    \
    asm volatile("s_nop 1\n\t"                                                \
                 "v_add_f32 %0, %0, %0 row_shr:2 bound_ctrl:0" : "+v"(x));    \
    asm volatile("s_nop 1\n\t"                                                \
                 "v_add_f32 %0, %0, %0 row_shr:4 bound_ctrl:0" : "+v"(x));    \
    asm volatile("s_nop 1\n\t"                                                \
                 "v_add_f32 %0, %0, %0 row_shr:8 bound_ctrl:0" : "+v"(x));    \
    asm volatile("s_nop 1\n\t"                                                \
                 "v_add_f32 %0, %0, %0 row_bcast:15 row_mask:0xa" : "+v"(x)); \
    asm volatile("s_nop 1\n\t"                                                \
                 "v_add_f32 %0, %0, %0 row_bcast:31 row_mask:0xc" : "+v"(x));

__device__ __forceinline__ float wave_total(float x)
{
    return __uint_as_float(__builtin_amdgcn_readlane(__float_as_uint(x), 63));
}

// ---------------------------------------------------------------------------
// Single fused kernel (R24 — session best, 24.9 us). Structure:
//  * truncated sparse carry: r[S,c] = sum_{s'>=S} a[s',c]*exp(-(t_s'-t_S)/T)
//    over the next 256 events only (truncation ~1e-5, 8.4 sigma margin);
//    a is 2-hot -> 256 threads scatter 2 atomic LDS adds into accs[2048].
//  * scatter loads + pred prefetches issued FIRST (latency hides under head).
//  * active-segment-only loss: p in {0,1} -> only 2 of 4 segments read/eval'd.
//  * DPP VALU-pipe wave reductions (no DS traffic in the hot loop).
// ---------------------------------------------------------------------------
__global__ __launch_bounds__(256) void tdl_loss_kernel(
    const float* __restrict__ pred, const float* __restrict__ target,
    float* __restrict__ partials)
{
    const int blk = blockIdx.x;
    const int b = blk >> 8;              // / NCH
    const int k = blk & (NCH - 1);
    const int s0 = k * CL;
    const int tid = threadIdx.x;
    const int wv  = (tid >> 6) & 1;      // 0: H-pair, 1: W-pair
    const int rh  = tid >> 7;            // 0: rows 15..8, 1: rows 7..0
    const int ln  = tid & 63;

    __shared__ float accs[NC];           // 8 KiB sparse-carry accumulator
    __shared__ f32x4 ev[CL];             // {dec, p, h, w}
    __shared__ float sh4[4];

    const int lc   = ln * 4;             // lane offset within a 256-ch quarter
    const int segA = wv * 2;             // even segment of my pair
    const size_t pbase = (size_t)b * NS * NC;
    const int itop = rh ? (CL / 2 - 1) : (CL - 1);  // 7 or 15

    // ---- ISSUE FIRST: scatter loads (zero deps; latency hides under head)
    const int sc = s0 + CL + tid;
    f32x4 evt = {0.0f, 0.0f, 0.0f, 0.0f};
    float tb0 = 0.0f;
    const bool sc_ok = (sc < NS);
    if (sc_ok) {
        evt = *((const f32x4*)target + (size_t)b * NS + sc);
        tb0 = target[((size_t)b * NS + s0 + CL) * 4];
    }

    // ---- EARLY global p for my first two rows -> pred prefetch issues
    //      before the staging barrier.
    const float pt0 = target[((size_t)b * NS + s0 + itop) * 4 + 3];
    const float pt1 = target[((size_t)b * NS + s0 + itop - 1) * 4 + 3];
    f32x4 pf0[2], pf1[2];
    {
        const float* pr = pred + pbase + (size_t)(s0 + itop) * NC
                          + (segA + (int)pt0) * 512 + lc;
        pf0[0] = *(const f32x4*)pr; pf0[1] = *(const f32x4*)(pr + 256);
        const float* pr2 = pred + pbase + (size_t)(s0 + itop - 1) * NC
                           + (segA + (int)pt1) * 512 + lc;
        pf1[0] = *(const f32x4*)pr2; pf1[1] = *(const f32x4*)(pr2 + 256);
    }

    // ---- head: zero acc + stage ev rows
    {
        f32x4 z = {0.0f, 0.0f, 0.0f, 0.0f};
        ((f32x4*)accs)[tid] = z;
        ((f32x4*)accs)[256 + tid] = z;
    }
    if (tid < CL) {
        const float* tg = target + ((size_t)b * NS + s0 + tid) * 4;
        float t0 = tg[0];
        int s = s0 + tid;
        float dec = (s == NS - 1 || s == 0) ? 0.0f
                   : __expf(-(tg[4] - t0) * INV_TEMP);   // tg[4] = t[s+1]
        f32x4 e; e.x = dec; e.y = tg[3]; e.z = tg[1]; e.w = tg[2];
        ev[tid] = e;
    }
    __syncthreads();

    // ---- sparse carry scatter (evt already in registers)
    if (sc_ok) {
        const float w = __expf(-(evt.x - tb0) * INV_TEMP);
        const int hh = (int)evt.y;
        const int ww = (int)evt.z;
        if (evt.w != 0.0f) {             // p==1 -> segments H1, W1
            atomicAdd(&accs[512 + hh], w);
            atomicAdd(&accs[1536 + ww], w);
        } else {                         // p==0 -> segments H0, W0
            atomicAdd(&accs[hh], w);
            atomicAdd(&accs[1024 + ww], w);
        }
    }
    __syncthreads();

    // ---- carry read: vA/vB from acc (exp2 domain)
    float vA[8], vB[8];
#pragma unroll
    for (int q = 0; q < 2; ++q) {
        f32x4 ra = *(const f32x4*)&accs[segA * 512 + q * 256 + lc];
        f32x4 rb = *(const f32x4*)&accs[(segA + 1) * 512 + q * 256 + lc];
#pragma unroll
        for (int j = 0; j < 4; ++j) {
            vA[q*4+j] = ra[j] * LOG2E;
            vB[q*4+j] = rb[j] * LOG2E;
        }
    }

    // rh=1 waves: replay rows 15..8 scan-only to derive carry at row 7
    if (rh) {
#pragma unroll
        for (int i = CL - 1; i >= CL / 2; --i) {
            f32x4 e = ev[i];
            const float d    = e.x;
            const float pv   = e.y;
            const float idxf = wv ? e.w : e.z;
            const float aA = (1.0f - pv) * LOG2E;
            const float aB = pv * LOG2E;
#pragma unroll
            for (int q = 0; q < 2; ++q) {
#pragma unroll
                for (int j = 0; j < 4; ++j) {
                    const int id = q * 4 + j;
                    const float myc = (float)(q * 256 + lc + j);
                    const bool m = (idxf == myc);
                    vA[id] = fmaf(vA[id], d, m ? aA : 0.0f);
                    vB[id] = fmaf(vB[id], d, m ? aB : 0.0f);
                }
            }
        }
    }

    float acc = 0.0f;
#pragma unroll
    for (int r = 0; r < 8; ++r) {
        const int i = itop - r;
        f32x4 cur0 = pf0[0], cur1 = pf0[1];
        pf0[0] = pf1[0]; pf0[1] = pf1[1];
        if (r < 6) {                     // row i-2 still in my range
            const int pa = (int)ev[i - 2].y;
            const float* pr = pred + pbase + (size_t)(s0 + i - 2) * NC
                              + (segA + pa) * 512 + lc;
            pf1[0] = *(const f32x4*)pr; pf1[1] = *(const f32x4*)(pr + 256);
        }

        f32x4 e = ev[i];
        const float d    = e.x;
        const float pv   = e.y;                    // 0.0 or 1.0 exactly
        const float idxf = wv ? e.w : e.z;         // w for W-pair, h for H-pair
        const float aA = (1.0f - pv) * LOG2E;
        const float aB = pv * LOG2E;

        float ser = 0.0f, dot = 0.0f, sep = 0.0f;
#pragma unroll
        for (int q = 0; q < 2; ++q) {
            const f32x4 cq = q ? cur1 : cur0;
#pragma unroll
            for (int j = 0; j < 4; ++j) {
                const int id = q * 4 + j;
                const float myc = (float)(q * 256 + lc + j);
                const bool m = (idxf == myc);
                vA[id] = fmaf(vA[id], d, m ? aA : 0.0f);  // scan both segs
                vB[id] = fmaf(vB[id], d, m ? aB : 0.0f);
                const float vs = (pv != 0.0f) ? vB[id] : vA[id];  // active
                const float ex = exp2f(vs);
                const float pj = cq[j];
                ser += ex;
                dot = fmaf(ex, pj, dot);
                sep += __expf(pj);
            }
        }

        // 64-lane reductions on the VALU pipe (DPP), no DS traffic
        WAVE_SUM_DPP(ser)
        WAVE_SUM_DPP(dot)
        WAVE_SUM_DPP(sep)
        const float serT = wave_total(ser);
        const float dotT = wave_total(dot);
        const float sepT = wave_total(sep);
        acc += __logf(sepT) - dotT * __builtin_amdgcn_rcpf(serT);
    }

    if (ln == 0) sh4[tid >> 6] = acc;    // one writer per wave
    __syncthreads();
    if (tid == 0) partials[blk] = sh4[0] + sh4[1] + sh4[2] + sh4[3];
}

// ---------------------------------------------------------------------------
// Tiny reduce — 1 block, 256 threads, 4 KB of partials -> out[0].
// ---------------------------------------------------------------------------
__global__ __launch_bounds__(256) void tdl_reduce_kernel(
    const float* __restrict__ partials, float* __restrict__ out)
{
    const int tid = threadIdx.x;
    __shared__ float sh4[4];

    float s = 0.0f;
#pragma unroll
    for (int i = 0; i < LOSS_NBLK / 256; ++i)
        s += partials[i * 256 + tid];
#pragma unroll
    for (int off = 32; off > 0; off >>= 1)
        s += __shfl_xor(s, off, 64);
    if ((tid & 63) == 0) sh4[tid >> 6] = s;
    __syncthreads();
    if (tid == 0)
        out[0] = (sh4[0] + sh4[1] + sh4[2] + sh4[3])
                 * (1.0f / ((float)NB * (float)NS));
}

// ---------------------------------------------------------------------------
extern "C" void kernel_launch(void* const* d_in, const int* in_sizes, int n_in,
                              void* d_out, int out_size, void* d_ws, size_t ws_size,
                              hipStream_t stream)
{
    const float* pred   = (const float*)d_in[0];
    const float* target = (const float*)d_in[1];
    float* out      = (float*)d_out;
    float* partials = (float*)d_ws;      // 4 KiB

    tdl_loss_kernel<<<NB * NCH, 256, 0, stream>>>(pred, target, partials);
    tdl_reduce_kernel<<<1, 256, 0, stream>>>(partials, out);
}